// Round 7
// baseline (363.793 us; speedup 1.0000x reference)
//
#include <hip/hip_runtime.h>
#include <math.h>

// Problem constants (fixed by the reference)
#define B_SZ    2
#define LSEQ    1024
#define DIM     1024
#define DSTATE  16
#define DCONV   4
#define DIN     2048          // d_inner
#define MROWS   (B_SZ * LSEQ) // 2048
#define CH      (B_SZ * DIN)  // 4096 channels
#define NCHUNK  32
#define LC      (LSEQ / NCHUNK)  // 32

typedef short  bf16x8 __attribute__((ext_vector_type(8)));
typedef float  f32x4  __attribute__((ext_vector_type(4)));

__device__ __forceinline__ float softplus_f(float x) {
    return fmaxf(x, 0.0f) + log1pf(__expf(-fabsf(x)));
}

__device__ __forceinline__ unsigned short f2bf(float x) {
    unsigned u = __float_as_uint(x);
    u = (u + 0x7FFF + ((u >> 16) & 1)) >> 16;
    return (unsigned short)u;
}

__device__ __forceinline__ float bf2f(unsigned short u) {
    return __uint_as_float((unsigned)u << 16);
}

__device__ __forceinline__ void load_lds16(const void* g, void* l) {
    __builtin_amdgcn_global_load_lds(
        (const __attribute__((address_space(1))) unsigned int*)g,
        (__attribute__((address_space(3))) unsigned int*)l, 16, 0, 0);
}

// ---------------------------------------------------------------------------
// f32 -> bf16 conversion (vectorized, 4 elems/thread)
// ---------------------------------------------------------------------------
__global__ __launch_bounds__(256) void f32_to_bf16(
    const float* __restrict__ src, unsigned short* __restrict__ dst, int n)
{
    int i = (blockIdx.x * 256 + threadIdx.x) * 4;
    if (i >= n) return;
    const float4 v = *reinterpret_cast<const float4*>(src + i);
    ushort4 o;
    o.x = f2bf(v.x); o.y = f2bf(v.y); o.z = f2bf(v.z); o.w = f2bf(v.w);
    *reinterpret_cast<ushort4*>(dst + i) = o;
}

// ---------------------------------------------------------------------------
// zero / copy utility kernels (graph-capture-safe init for atomic targets)
// ---------------------------------------------------------------------------
__global__ __launch_bounds__(256) void zero_f32(float* __restrict__ p, int n)
{
    int i = (blockIdx.x * 256 + threadIdx.x) * 4;
    if (i < n) *reinterpret_cast<float4*>(p + i) = make_float4(0.f, 0.f, 0.f, 0.f);
}

__global__ __launch_bounds__(256) void copy_f32(
    const float* __restrict__ s, float* __restrict__ d, int n)
{
    int i = (blockIdx.x * 256 + threadIdx.x) * 4;
    if (i < n) *reinterpret_cast<float4*>(d + i) = *reinterpret_cast<const float4*>(s + i);
}

// delta = softplus(delta_raw + b_dt[col]) in place, [MROWS, DIN]
__global__ __launch_bounds__(256) void finalize_delta(
    float* __restrict__ delta, const float* __restrict__ b_dt)
{
    int i = (blockIdx.x * 256 + threadIdx.x) * 4;
    float4 v = *reinterpret_cast<float4*>(delta + i);
    const float4 b = *reinterpret_cast<const float4*>(b_dt + (i & (DIN - 1)));
    v.x = softplus_f(v.x + b.x);
    v.y = softplus_f(v.y + b.y);
    v.z = softplus_f(v.z + b.z);
    v.w = softplus_f(v.w + b.w);
    *reinterpret_cast<float4*>(delta + i) = v;
}

// ---------------------------------------------------------------------------
// bf16 MFMA NT GEMM: C[m,n] += sum_k A[m,k]*B[n,k], fp32 atomic accumulate.
// Tile 128x128, BK=32, 256 thr = 4 waves (2x2); wave = 64x64 = 4x4 frags.
// Double-buffered LDS 2x(8+8)=32 KB -> up to 5 blocks/CU; split-K grids give
// >=4 blocks/CU so the per-step vmcnt(0) drain overlaps across blocks (m114).
// LDS layout k-slot-major (ushort idx = ks*(128*8) + row*8): fragment
// ds_read_b128 is conflict-free (0 conflicts measured r5/r6); global source
// address carries the permutation, LDS dest stays lane-linear.
// blockIdx.z = K-slice of Ksub columns; C must be pre-initialized.
// ---------------------------------------------------------------------------
template <int ATOMIC>
__global__ __launch_bounds__(256, 4) void gemm_bf16(
    const unsigned short* __restrict__ A, const unsigned short* __restrict__ Bm,
    float* __restrict__ C, int M, int N, int K, int Ksub)
{
    __shared__ unsigned short As[2][128 * 32];   // 2 x 8 KB
    __shared__ unsigned short Bs[2][128 * 32];   // 2 x 8 KB

    const int t    = threadIdx.x;
    const int lane = t & 63;
    const int w    = t >> 6;          // wave 0..3
    const int wr   = w >> 1;          // wave row (0..1) -> 64 rows
    const int wc   = w & 1;           // wave col (0..1) -> 64 cols
    const int row0 = blockIdx.y * 128;
    const int col0 = blockIdx.x * 128;
    const int kbase = blockIdx.z * Ksub;

    const int lrow  = lane & 15;
    const int kslot = lane >> 4;      // 0..3

    f32x4 acc[4][4];
    #pragma unroll
    for (int i = 0; i < 4; ++i)
        #pragma unroll
        for (int j = 0; j < 4; ++j)
            acc[i][j] = (f32x4){0.f, 0.f, 0.f, 0.f};

    const int wbase = w << 10;        // wave's 1 KB slot per 256-unit pass

    // stage one 128x32 A-tile + 128x32 B-tile into buffer `buf` (8 KB each)
    auto stage = [&](int k0, int buf) {
        #pragma unroll
        for (int p = 0; p < 2; ++p) {
            const int u   = t + p * 256;     // 16B-unit 0..511: u = ks*128+row
            const int ks  = u >> 7;          // 0..3 (8-elem K-group)
            const int row = u & 127;
            load_lds16(A  + (size_t)(row0 + row) * K + k0 + ks * 8,
                       (char*)&As[buf][0] + p * 4096 + wbase);
            load_lds16(Bm + (size_t)(col0 + row) * K + k0 + ks * 8,
                       (char*)&Bs[buf][0] + p * 4096 + wbase);
        }
    };

    const int NT = Ksub >> 5;
    stage(kbase, 0);
    __syncthreads();

    int cur = 0;
    for (int kt = 0; kt < NT; ++kt) {
        if (kt + 1 < NT) stage(kbase + ((kt + 1) << 5), cur ^ 1);

        bf16x8 af[4], bf[4];
        #pragma unroll
        for (int i = 0; i < 4; ++i)
            af[i] = *reinterpret_cast<const bf16x8*>(
                &As[cur][kslot * (128 * 8) + (wr * 64 + i * 16 + lrow) * 8]);
        #pragma unroll
        for (int j = 0; j < 4; ++j)
            bf[j] = *reinterpret_cast<const bf16x8*>(
                &Bs[cur][kslot * (128 * 8) + (wc * 64 + j * 16 + lrow) * 8]);
        #pragma unroll
        for (int i = 0; i < 4; ++i)
            #pragma unroll
            for (int j = 0; j < 4; ++j)
                acc[i][j] = __builtin_amdgcn_mfma_f32_16x16x32_bf16(af[i], bf[j], acc[i][j], 0, 0, 0);

        __syncthreads();   // drains vmcnt(0): next buffer staged & ready
        cur ^= 1;
    }

    // epilogue: D mapping col=lane&15, row=(lane>>4)*4+q
    #pragma unroll
    for (int i = 0; i < 4; ++i) {
        const int r0 = row0 + wr * 64 + i * 16 + (lane >> 4) * 4;
        #pragma unroll
        for (int j = 0; j < 4; ++j) {
            const int c = col0 + wc * 64 + j * 16 + lrow;
            #pragma unroll
            for (int q = 0; q < 4; ++q) {
                const int r = r0 + q;
                if (ATOMIC) atomicAdd(&C[(size_t)r * N + c], acc[i][j][q]);
                else        C[(size_t)r * N + c] = acc[i][j][q];
            }
        }
    }
}

// ---------------------------------------------------------------------------
// Causal depthwise conv(4) + bias + SiLU -> bf16 xcb.
// ---------------------------------------------------------------------------
__global__ __launch_bounds__(256) void conv_silu(
    const float* __restrict__ xz, const float* __restrict__ Wc,
    const float* __restrict__ bc, unsigned short* __restrict__ xcb)
{
    int idx = blockIdx.x * 256 + threadIdx.x;      // m*DIN + e
    int e = idx & (DIN - 1);
    int m = idx >> 11;
    int l = m & (LSEQ - 1);

    const float4 w = reinterpret_cast<const float4*>(Wc)[e];
    float acc = bc[e];
    if (l >= 3) acc = fmaf(xz[(size_t)(m - 3) * (2 * DIN) + e], w.x, acc);
    if (l >= 2) acc = fmaf(xz[(size_t)(m - 2) * (2 * DIN) + e], w.y, acc);
    if (l >= 1) acc = fmaf(xz[(size_t)(m - 1) * (2 * DIN) + e], w.z, acc);
    acc = fmaf(xz[(size_t)m * (2 * DIN) + e], w.w, acc);
    float s = acc / (1.0f + __expf(-acc));
    xcb[idx] = f2bf(s);
}

// ---------------------------------------------------------------------------
// B_t / C_t projections (reads bf16 xcb, fp32 accumulate).
// ---------------------------------------------------------------------------
__global__ __launch_bounds__(256) void bc_proj(
    const unsigned short* __restrict__ xcb, const float* __restrict__ WB,
    const float* __restrict__ WC, float* __restrict__ Bt, float* __restrict__ Ct)
{
    __shared__ float row[DIN];
    const int m = blockIdx.x;
    for (int i = threadIdx.x; i < DIN; i += 256)
        row[i] = bf2f(xcb[(size_t)m * DIN + i]);
    __syncthreads();

    const int o   = threadIdx.x >> 3;
    const int sub = threadIdx.x & 7;
    const float* W = (o < DSTATE) ? (WB + (size_t)o * DIN) : (WC + (size_t)(o - DSTATE) * DIN);
    float p = 0.0f;
    for (int j = sub; j < DIN; j += 8)
        p = fmaf(row[j], W[j], p);
    p += __shfl_xor(p, 1, 8);
    p += __shfl_xor(p, 2, 8);
    p += __shfl_xor(p, 4, 8);
    if (sub == 0) {
        if (o < DSTATE) Bt[(size_t)m * DSTATE + o] = p;
        else            Ct[(size_t)m * DSTATE + (o - DSTATE)] = p;
    }
}

// ---------------------------------------------------------------------------
// Chunked selective scan — pass 1: per-chunk local scan from h=0.
// ---------------------------------------------------------------------------
__global__ __launch_bounds__(256) void scan_pass1(
    const float* __restrict__ delta, const unsigned short* __restrict__ xcb,
    const float* __restrict__ Bt, const float* __restrict__ A_log,
    float* __restrict__ hfin, float* __restrict__ dsums)
{
    const int ge = blockIdx.x * 256 + threadIdx.x;
    const int c  = blockIdx.y;
    const int b  = ge >> 11;
    const int e  = ge & (DIN - 1);

    float A[DSTATE];
    #pragma unroll
    for (int s = 0; s < DSTATE; ++s) A[s] = -__expf(A_log[s]);

    float h[DSTATE] = {};
    float dsum = 0.0f;
    const int m0 = b * LSEQ + c * LC;

    for (int l = 0; l < LC; ++l) {
        const int m = m0 + l;
        const float dv = delta[(size_t)m * DIN + e];
        const float xv = bf2f(xcb[(size_t)m * DIN + e]);
        dsum += dv;
        const float dx = dv * xv;
        #pragma unroll
        for (int s = 0; s < DSTATE; ++s) {
            const float bv = Bt[(size_t)m * DSTATE + s];
            h[s] = fmaf(h[s], __expf(dv * A[s]), dx * bv);
        }
    }

    float4* hf = reinterpret_cast<float4*>(&hfin[((size_t)ge * NCHUNK + c) * DSTATE]);
    #pragma unroll
    for (int q = 0; q < 4; ++q)
        hf[q] = make_float4(h[4*q], h[4*q+1], h[4*q+2], h[4*q+3]);
    dsums[(size_t)ge * NCHUNK + c] = dsum;
}

// ---------------------------------------------------------------------------
// Pass 2: sequential combine over chunks (in place).
// ---------------------------------------------------------------------------
__global__ __launch_bounds__(256) void scan_pass2(
    float* __restrict__ hfin, const float* __restrict__ dsums,
    const float* __restrict__ A_log)
{
    const int t  = blockIdx.x * 256 + threadIdx.x;
    const int ge = t >> 4;
    const int s  = t & 15;
    const float A = -__expf(A_log[s]);

    float h = 0.0f;
    for (int c = 0; c < NCHUNK; ++c) {
        const size_t idx = ((size_t)ge * NCHUNK + c) * DSTATE + s;
        const float hf = hfin[idx];
        hfin[idx] = h;
        const float P = __expf(A * dsums[(size_t)ge * NCHUNK + c]);
        h = fmaf(P, h, hf);
    }
}

// ---------------------------------------------------------------------------
// Pass 3: re-run local scan with carry-in; fuse C-dot, D, silu(z); bf16 out.
// ---------------------------------------------------------------------------
__global__ __launch_bounds__(256) void scan_pass3(
    const float* __restrict__ delta, const unsigned short* __restrict__ xcb,
    const float* __restrict__ Bt, const float* __restrict__ Ct,
    const float* __restrict__ xz, const float* __restrict__ A_log,
    const float* __restrict__ Dv, const float* __restrict__ hcar,
    unsigned short* __restrict__ ygb)
{
    const int ge = blockIdx.x * 256 + threadIdx.x;
    const int c  = blockIdx.y;
    const int b  = ge >> 11;
    const int e  = ge & (DIN - 1);

    float A[DSTATE];
    #pragma unroll
    for (int s = 0; s < DSTATE; ++s) A[s] = -__expf(A_log[s]);

    float h[DSTATE];
    const float4* hc = reinterpret_cast<const float4*>(&hcar[((size_t)ge * NCHUNK + c) * DSTATE]);
    #pragma unroll
    for (int q = 0; q < 4; ++q) {
        const float4 v = hc[q];
        h[4*q]   = v.x; h[4*q+1] = v.y; h[4*q+2] = v.z; h[4*q+3] = v.w;
    }

    const float Dval = Dv[e];
    const int m0 = b * LSEQ + c * LC;

    for (int l = 0; l < LC; ++l) {
        const int m = m0 + l;
        const float dv = delta[(size_t)m * DIN + e];
        const float xv = bf2f(xcb[(size_t)m * DIN + e]);
        const float dx = dv * xv;
        float y = xv * Dval;
        #pragma unroll
        for (int s = 0; s < DSTATE; ++s) {
            const float bv = Bt[(size_t)m * DSTATE + s];
            const float cv = Ct[(size_t)m * DSTATE + s];
            h[s] = fmaf(h[s], __expf(dv * A[s]), dx * bv);
            y = fmaf(h[s], cv, y);
        }
        const float zv = xz[(size_t)m * (2 * DIN) + DIN + e];
        const float sz = zv / (1.0f + __expf(-zv));
        ygb[(size_t)m * DIN + e] = f2bf(y * sz);
    }
}

// ---------------------------------------------------------------------------
extern "C" void kernel_launch(void* const* d_in, const int* in_sizes, int n_in,
                              void* d_out, int out_size, void* d_ws, size_t ws_size,
                              hipStream_t stream)
{
    const float* x      = (const float*)d_in[0];
    const float* W_in   = (const float*)d_in[1];
    const float* W_conv = (const float*)d_in[2];
    const float* b_conv = (const float*)d_in[3];
    const float* W_dt   = (const float*)d_in[4];
    const float* b_dt   = (const float*)d_in[5];
    const float* W_B    = (const float*)d_in[6];
    const float* W_C    = (const float*)d_in[7];
    const float* A_log  = (const float*)d_in[8];
    const float* Dvec   = (const float*)d_in[9];
    const float* W_out  = (const float*)d_in[10];
    float* out = (float*)d_out;

    // Workspace layout (84.75 MB total):
    float* ws    = (float*)d_ws;
    float* xz    = ws;                                  // [2048,4096] f32  32 MB
    float* delta = xz + (size_t)MROWS * 2 * DIN;        // [2048,2048] f32  16 MB
    float* Bt    = delta + (size_t)MROWS * DIN;         // [2048,16]   f32
    float* Ct    = Bt + (size_t)MROWS * DSTATE;         // [2048,16]   f32
    float* hfin  = Ct + (size_t)MROWS * DSTATE;         // [4096,32,16] f32  8 MB
    float* dsums = hfin + (size_t)CH * NCHUNK * DSTATE; // [4096,32]   f32  0.5 MB
    unsigned short* xb   = (unsigned short*)(dsums + (size_t)CH * NCHUNK); // [2048,1024] bf16 4 MB
    unsigned short* wbuf = xb + (size_t)MROWS * DIM;        // up to 4M bf16   8 MB
    unsigned short* xcb  = wbuf + (size_t)4 * 1024 * 1024;  // [2048,2048] bf16 8 MB
    unsigned short* ygb  = xcb + (size_t)MROWS * DIN;       // [2048,2048] bf16 8 MB

    // 1. xz = x @ W_in^T   [2048,4096], K=1024 split 2-way -> 1024 blocks
    f32_to_bf16<<<(MROWS * DIM) / 1024, 256, 0, stream>>>(x, xb, MROWS * DIM);
    f32_to_bf16<<<(2 * DIN * DIM) / 1024, 256, 0, stream>>>(W_in, wbuf, 2 * DIN * DIM);
    zero_f32<<<(MROWS * 2 * DIN) / 1024, 256, 0, stream>>>(xz, MROWS * 2 * DIN);
    gemm_bf16<1><<<dim3((2 * DIN) / 128, MROWS / 128, 2), 256, 0, stream>>>(
        xb, wbuf, xz, MROWS, 2 * DIN, DIM, DIM / 2);

    // 2. causal conv + silu -> xcb (bf16)
    conv_silu<<<(MROWS * DIN) / 256, 256, 0, stream>>>(xz, W_conv, b_conv, xcb);

    // 3. delta_raw = xcb @ W_dt^T  (K=2048 split 4-way -> 1024 blocks)
    zero_f32<<<(MROWS * DIN) / 1024, 256, 0, stream>>>(delta, MROWS * DIN);
    f32_to_bf16<<<(DIN * DIN) / 1024, 256, 0, stream>>>(W_dt, wbuf, DIN * DIN);
    gemm_bf16<1><<<dim3(DIN / 128, MROWS / 128, 4), 256, 0, stream>>>(
        xcb, wbuf, delta, MROWS, DIN, DIN, DIN / 4);
    finalize_delta<<<(MROWS * DIN) / 1024, 256, 0, stream>>>(delta, b_dt);

    // 4. B_t, C_t projections
    bc_proj<<<MROWS, 256, 0, stream>>>(xcb, W_B, W_C, Bt, Ct);

    // 5. chunked selective scan -> ygb (bf16)
    scan_pass1<<<dim3(CH / 256, NCHUNK), 256, 0, stream>>>(
        delta, xcb, Bt, A_log, hfin, dsums);
    scan_pass2<<<(CH * DSTATE) / 256, 256, 0, stream>>>(hfin, dsums, A_log);
    scan_pass3<<<dim3(CH / 256, NCHUNK), 256, 0, stream>>>(
        delta, xcb, Bt, Ct, xz, A_log, Dvec, hfin, ygb);

    // 6. out = x + ygb @ W_out^T  (K=2048 split 4-way -> 512 blocks)
    copy_f32<<<(MROWS * DIM) / 1024, 256, 0, stream>>>(x, out, MROWS * DIM);
    f32_to_bf16<<<(DIM * DIN) / 1024, 256, 0, stream>>>(W_out, wbuf, DIM * DIN);
    gemm_bf16<1><<<dim3(DIM / 128, MROWS / 128, 4), 256, 0, stream>>>(
        ygb, wbuf, out, MROWS, DIM, DIN, DIN / 4);
}

// Round 8
// 274.862 us; speedup vs baseline: 1.3235x; 1.3235x over previous
//
#include <hip/hip_runtime.h>
#include <math.h>

// Problem constants (fixed by the reference)
#define B_SZ    2
#define LSEQ    1024
#define DIM     1024
#define DSTATE  16
#define DCONV   4
#define DIN     2048          // d_inner
#define MROWS   (B_SZ * LSEQ) // 2048
#define CH      (B_SZ * DIN)  // 4096 channels
#define NCHUNK  32
#define LC      (LSEQ / NCHUNK)  // 32

typedef short  bf16x8 __attribute__((ext_vector_type(8)));
typedef float  f32x4  __attribute__((ext_vector_type(4)));

__device__ __forceinline__ float softplus_f(float x) {
    return fmaxf(x, 0.0f) + log1pf(__expf(-fabsf(x)));
}

__device__ __forceinline__ unsigned short f2bf(float x) {
    unsigned u = __float_as_uint(x);
    u = (u + 0x7FFF + ((u >> 16) & 1)) >> 16;
    return (unsigned short)u;
}

__device__ __forceinline__ float bf2f(unsigned short u) {
    return __uint_as_float((unsigned)u << 16);
}

__device__ __forceinline__ void load_lds16(const void* g, void* l) {
    __builtin_amdgcn_global_load_lds(
        (const __attribute__((address_space(1))) unsigned int*)g,
        (__attribute__((address_space(3))) unsigned int*)l, 16, 0, 0);
}

// ---------------------------------------------------------------------------
// f32 -> bf16 conversion (vectorized, 4 elems/thread)
// ---------------------------------------------------------------------------
__global__ __launch_bounds__(256) void f32_to_bf16(
    const float* __restrict__ src, unsigned short* __restrict__ dst, int n)
{
    int i = (blockIdx.x * 256 + threadIdx.x) * 4;
    if (i >= n) return;
    const float4 v = *reinterpret_cast<const float4*>(src + i);
    ushort4 o;
    o.x = f2bf(v.x); o.y = f2bf(v.y); o.z = f2bf(v.z); o.w = f2bf(v.w);
    *reinterpret_cast<ushort4*>(dst + i) = o;
}

// ---------------------------------------------------------------------------
// delta = softplus(P0 + P1 + b_dt[col]); P1 split across two regions by row.
// P1lo valid for rows 0..1023 (idx r*DIN+c); P1hi is pre-offset so that
// P1hi[r*DIN+c] lands at region[(r-1024)*DIN+c].
// ---------------------------------------------------------------------------
__global__ __launch_bounds__(256) void finalize_delta(
    float* __restrict__ delta, const float* __restrict__ P1lo,
    const float* __restrict__ P1hi, const float* __restrict__ b_dt)
{
    int i = (blockIdx.x * 256 + threadIdx.x) * 4;
    int r = i >> 11;
    const float* p1 = (r < 1024) ? P1lo : P1hi;
    float4 v = *reinterpret_cast<float4*>(delta + i);
    const float4 u = *reinterpret_cast<const float4*>(p1 + i);
    const float4 b = *reinterpret_cast<const float4*>(b_dt + (i & (DIN - 1)));
    v.x = softplus_f(v.x + u.x + b.x);
    v.y = softplus_f(v.y + u.y + b.y);
    v.z = softplus_f(v.z + u.z + b.z);
    v.w = softplus_f(v.w + u.w + b.w);
    *reinterpret_cast<float4*>(delta + i) = v;
}

// out = x + Q0 + Q1 + Q2 + Q3   [MROWS*DIM]
__global__ __launch_bounds__(256) void out_combine(
    const float* __restrict__ x, const float* __restrict__ Q0,
    const float* __restrict__ Q1, const float* __restrict__ Q2,
    const float* __restrict__ Q3, float* __restrict__ out)
{
    int i = (blockIdx.x * 256 + threadIdx.x) * 4;
    const float4 a = *reinterpret_cast<const float4*>(x + i);
    const float4 q0 = *reinterpret_cast<const float4*>(Q0 + i);
    const float4 q1 = *reinterpret_cast<const float4*>(Q1 + i);
    const float4 q2 = *reinterpret_cast<const float4*>(Q2 + i);
    const float4 q3 = *reinterpret_cast<const float4*>(Q3 + i);
    float4 o;
    o.x = a.x + ((q0.x + q1.x) + (q2.x + q3.x));
    o.y = a.y + ((q0.y + q1.y) + (q2.y + q3.y));
    o.z = a.z + ((q0.z + q1.z) + (q2.z + q3.z));
    o.w = a.w + ((q0.w + q1.w) + (q2.w + q3.w));
    *reinterpret_cast<float4*>(out + i) = o;
}

// ---------------------------------------------------------------------------
// bf16 MFMA NT GEMM: C[m,n] = sum_k A[m,k]*B[n,k], fp32 plain stores only.
// Tile 128x128, BK=64, 256 thr = 4 waves (2x2); wave = 64x64 = 4x4 frags.
// Double-buffered LDS 2x(16+16)=64 KB -> 2 blocks/CU; 32 MFMA/wave/barrier.
// LDS k-slot-major (ushort idx = ks8*(128*8)+row*8): fragment ds_read_b128 is
// conflict-free (0 conflicts measured r5/r6); global source address carries
// the permutation, LDS dest stays lane-linear (global_load_lds requirement).
// blockIdx.z = K-slice of Ksub; partial outputs go to separate buffers:
//   MODE 0: C0[r*N+c]                       (single slice)
//   MODE 1: z0->C0; z1-> (row<1024 ? C1 : C2)[r*N+c]   (C2 pre-offset)
//   MODE 2: {C0,C1,C2,C3}[z][r*N+c]
// ---------------------------------------------------------------------------
template <int MODE>
__global__ __launch_bounds__(256) void gemm_bf16(
    const unsigned short* __restrict__ A, const unsigned short* __restrict__ Bm,
    int M, int N, int K, int Ksub,
    float* __restrict__ C0, float* __restrict__ C1,
    float* __restrict__ C2, float* __restrict__ C3)
{
    __shared__ unsigned short As[2][128 * 64];   // 2 x 16 KB
    __shared__ unsigned short Bs[2][128 * 64];   // 2 x 16 KB

    const int t    = threadIdx.x;
    const int lane = t & 63;
    const int w    = t >> 6;          // wave 0..3
    const int wr   = w >> 1;          // wave row (0..1) -> 64 rows
    const int wc   = w & 1;           // wave col (0..1) -> 64 cols
    const int row0 = blockIdx.y * 128;
    const int col0 = blockIdx.x * 128;
    const int z     = blockIdx.z;
    const int kbase = z * Ksub;

    const int lrow  = lane & 15;
    const int kslot = lane >> 4;      // 0..3

    // partial-buffer select (block-uniform)
    float* C = C0;
    if (MODE == 1 && z == 1) C = (row0 < 1024) ? C1 : C2;
    if (MODE == 2) C = (z == 0) ? C0 : (z == 1) ? C1 : (z == 2) ? C2 : C3;

    f32x4 acc[4][4];
    #pragma unroll
    for (int i = 0; i < 4; ++i)
        #pragma unroll
        for (int j = 0; j < 4; ++j)
            acc[i][j] = (f32x4){0.f, 0.f, 0.f, 0.f};

    const int wbase = w << 10;        // wave's 1 KB slot per 256-unit pass

    // stage one 128x64 A-tile + 128x64 B-tile into buffer `buf` (16 KB each)
    auto stage = [&](int k0, int buf) {
        #pragma unroll
        for (int p = 0; p < 4; ++p) {
            const int u   = t + p * 256;     // 16B-unit 0..1023: u = ks8*128+row
            const int ks8 = u >> 7;          // 0..7 (8-elem K-group)
            const int row = u & 127;
            load_lds16(A  + (size_t)(row0 + row) * K + k0 + ks8 * 8,
                       (char*)&As[buf][0] + p * 4096 + wbase);
            load_lds16(Bm + (size_t)(col0 + row) * K + k0 + ks8 * 8,
                       (char*)&Bs[buf][0] + p * 4096 + wbase);
        }
    };

    const int NT = Ksub >> 6;
    stage(kbase, 0);
    __syncthreads();

    int cur = 0;
    for (int kt = 0; kt < NT; ++kt) {
        if (kt + 1 < NT) stage(kbase + ((kt + 1) << 6), cur ^ 1);

        #pragma unroll
        for (int s = 0; s < 2; ++s) {       // two 32-K sub-steps
            bf16x8 af[4], bf[4];
            #pragma unroll
            for (int i = 0; i < 4; ++i)
                af[i] = *reinterpret_cast<const bf16x8*>(
                    &As[cur][(s * 4 + kslot) * (128 * 8) + (wr * 64 + i * 16 + lrow) * 8]);
            #pragma unroll
            for (int j = 0; j < 4; ++j)
                bf[j] = *reinterpret_cast<const bf16x8*>(
                    &Bs[cur][(s * 4 + kslot) * (128 * 8) + (wc * 64 + j * 16 + lrow) * 8]);
            #pragma unroll
            for (int i = 0; i < 4; ++i)
                #pragma unroll
                for (int j = 0; j < 4; ++j)
                    acc[i][j] = __builtin_amdgcn_mfma_f32_16x16x32_bf16(af[i], bf[j], acc[i][j], 0, 0, 0);
        }
        __syncthreads();   // drains vmcnt(0): next buffer staged & ready
        cur ^= 1;
    }

    // epilogue: D mapping col=lane&15, row=(lane>>4)*4+q
    #pragma unroll
    for (int i = 0; i < 4; ++i) {
        const int r0 = row0 + wr * 64 + i * 16 + (lane >> 4) * 4;
        #pragma unroll
        for (int j = 0; j < 4; ++j) {
            const int c = col0 + wc * 64 + j * 16 + lrow;
            #pragma unroll
            for (int q = 0; q < 4; ++q) {
                const int r = r0 + q;
                C[(size_t)r * N + c] = acc[i][j][q];
            }
        }
    }
}

// ---------------------------------------------------------------------------
// Causal depthwise conv(4) + bias + SiLU -> bf16 xcb.
// ---------------------------------------------------------------------------
__global__ __launch_bounds__(256) void conv_silu(
    const float* __restrict__ xz, const float* __restrict__ Wc,
    const float* __restrict__ bc, unsigned short* __restrict__ xcb)
{
    int idx = blockIdx.x * 256 + threadIdx.x;      // m*DIN + e
    int e = idx & (DIN - 1);
    int m = idx >> 11;
    int l = m & (LSEQ - 1);

    const float4 w = reinterpret_cast<const float4*>(Wc)[e];
    float acc = bc[e];
    if (l >= 3) acc = fmaf(xz[(size_t)(m - 3) * (2 * DIN) + e], w.x, acc);
    if (l >= 2) acc = fmaf(xz[(size_t)(m - 2) * (2 * DIN) + e], w.y, acc);
    if (l >= 1) acc = fmaf(xz[(size_t)(m - 1) * (2 * DIN) + e], w.z, acc);
    acc = fmaf(xz[(size_t)m * (2 * DIN) + e], w.w, acc);
    float s = acc / (1.0f + __expf(-acc));
    xcb[idx] = f2bf(s);
}

// ---------------------------------------------------------------------------
// B_t / C_t projections (reads bf16 xcb, fp32 accumulate).
// ---------------------------------------------------------------------------
__global__ __launch_bounds__(256) void bc_proj(
    const unsigned short* __restrict__ xcb, const float* __restrict__ WB,
    const float* __restrict__ WC, float* __restrict__ Bt, float* __restrict__ Ct)
{
    __shared__ float row[DIN];
    const int m = blockIdx.x;
    for (int i = threadIdx.x; i < DIN; i += 256)
        row[i] = bf2f(xcb[(size_t)m * DIN + i]);
    __syncthreads();

    const int o   = threadIdx.x >> 3;
    const int sub = threadIdx.x & 7;
    const float* W = (o < DSTATE) ? (WB + (size_t)o * DIN) : (WC + (size_t)(o - DSTATE) * DIN);
    float p = 0.0f;
    for (int j = sub; j < DIN; j += 8)
        p = fmaf(row[j], W[j], p);
    p += __shfl_xor(p, 1, 8);
    p += __shfl_xor(p, 2, 8);
    p += __shfl_xor(p, 4, 8);
    if (sub == 0) {
        if (o < DSTATE) Bt[(size_t)m * DSTATE + o] = p;
        else            Ct[(size_t)m * DSTATE + (o - DSTATE)] = p;
    }
}

// ---------------------------------------------------------------------------
// Chunked selective scan — pass 1: per-chunk local scan from h=0.
// ---------------------------------------------------------------------------
__global__ __launch_bounds__(256) void scan_pass1(
    const float* __restrict__ delta, const unsigned short* __restrict__ xcb,
    const float* __restrict__ Bt, const float* __restrict__ A_log,
    float* __restrict__ hfin, float* __restrict__ dsums)
{
    const int ge = blockIdx.x * 256 + threadIdx.x;
    const int c  = blockIdx.y;
    const int b  = ge >> 11;
    const int e  = ge & (DIN - 1);

    float A[DSTATE];
    #pragma unroll
    for (int s = 0; s < DSTATE; ++s) A[s] = -__expf(A_log[s]);

    float h[DSTATE] = {};
    float dsum = 0.0f;
    const int m0 = b * LSEQ + c * LC;

    for (int l = 0; l < LC; ++l) {
        const int m = m0 + l;
        const float dv = delta[(size_t)m * DIN + e];
        const float xv = bf2f(xcb[(size_t)m * DIN + e]);
        dsum += dv;
        const float dx = dv * xv;
        #pragma unroll
        for (int s = 0; s < DSTATE; ++s) {
            const float bv = Bt[(size_t)m * DSTATE + s];
            h[s] = fmaf(h[s], __expf(dv * A[s]), dx * bv);
        }
    }

    float4* hf = reinterpret_cast<float4*>(&hfin[((size_t)ge * NCHUNK + c) * DSTATE]);
    #pragma unroll
    for (int q = 0; q < 4; ++q)
        hf[q] = make_float4(h[4*q], h[4*q+1], h[4*q+2], h[4*q+3]);
    dsums[(size_t)ge * NCHUNK + c] = dsum;
}

// ---------------------------------------------------------------------------
// Pass 2: sequential combine over chunks (in place).
// ---------------------------------------------------------------------------
__global__ __launch_bounds__(256) void scan_pass2(
    float* __restrict__ hfin, const float* __restrict__ dsums,
    const float* __restrict__ A_log)
{
    const int t  = blockIdx.x * 256 + threadIdx.x;
    const int ge = t >> 4;
    const int s  = t & 15;
    const float A = -__expf(A_log[s]);

    float h = 0.0f;
    for (int c = 0; c < NCHUNK; ++c) {
        const size_t idx = ((size_t)ge * NCHUNK + c) * DSTATE + s;
        const float hf = hfin[idx];
        hfin[idx] = h;
        const float P = __expf(A * dsums[(size_t)ge * NCHUNK + c]);
        h = fmaf(P, h, hf);
    }
}

// ---------------------------------------------------------------------------
// Pass 3: re-run local scan with carry-in; fuse C-dot, D, silu(z); bf16 out.
// ---------------------------------------------------------------------------
__global__ __launch_bounds__(256) void scan_pass3(
    const float* __restrict__ delta, const unsigned short* __restrict__ xcb,
    const float* __restrict__ Bt, const float* __restrict__ Ct,
    const float* __restrict__ xz, const float* __restrict__ A_log,
    const float* __restrict__ Dv, const float* __restrict__ hcar,
    unsigned short* __restrict__ ygb)
{
    const int ge = blockIdx.x * 256 + threadIdx.x;
    const int c  = blockIdx.y;
    const int b  = ge >> 11;
    const int e  = ge & (DIN - 1);

    float A[DSTATE];
    #pragma unroll
    for (int s = 0; s < DSTATE; ++s) A[s] = -__expf(A_log[s]);

    float h[DSTATE];
    const float4* hc = reinterpret_cast<const float4*>(&hcar[((size_t)ge * NCHUNK + c) * DSTATE]);
    #pragma unroll
    for (int q = 0; q < 4; ++q) {
        const float4 v = hc[q];
        h[4*q]   = v.x; h[4*q+1] = v.y; h[4*q+2] = v.z; h[4*q+3] = v.w;
    }

    const float Dval = Dv[e];
    const int m0 = b * LSEQ + c * LC;

    for (int l = 0; l < LC; ++l) {
        const int m = m0 + l;
        const float dv = delta[(size_t)m * DIN + e];
        const float xv = bf2f(xcb[(size_t)m * DIN + e]);
        const float dx = dv * xv;
        float y = xv * Dval;
        #pragma unroll
        for (int s = 0; s < DSTATE; ++s) {
            const float bv = Bt[(size_t)m * DSTATE + s];
            const float cv = Ct[(size_t)m * DSTATE + s];
            h[s] = fmaf(h[s], __expf(dv * A[s]), dx * bv);
            y = fmaf(h[s], cv, y);
        }
        const float zv = xz[(size_t)m * (2 * DIN) + DIN + e];
        const float sz = zv / (1.0f + __expf(-zv));
        ygb[(size_t)m * DIN + e] = f2bf(y * sz);
    }
}

// ---------------------------------------------------------------------------
extern "C" void kernel_launch(void* const* d_in, const int* in_sizes, int n_in,
                              void* d_out, int out_size, void* d_ws, size_t ws_size,
                              hipStream_t stream)
{
    const float* x      = (const float*)d_in[0];
    const float* W_in   = (const float*)d_in[1];
    const float* W_conv = (const float*)d_in[2];
    const float* b_conv = (const float*)d_in[3];
    const float* W_dt   = (const float*)d_in[4];
    const float* b_dt   = (const float*)d_in[5];
    const float* W_B    = (const float*)d_in[6];
    const float* W_C    = (const float*)d_in[7];
    const float* A_log  = (const float*)d_in[8];
    const float* Dvec   = (const float*)d_in[9];
    const float* W_out  = (const float*)d_in[10];
    float* out = (float*)d_out;

    // Workspace layout (84.75 MB total, same as r4-r7):
    float* ws    = (float*)d_ws;
    float* xz    = ws;                                  // [2048,4096] f32  32 MB
    float* delta = xz + (size_t)MROWS * 2 * DIN;        // [2048,2048] f32  16 MB
    float* Bt    = delta + (size_t)MROWS * DIN;         // [2048,16]   f32
    float* Ct    = Bt + (size_t)MROWS * DSTATE;         // [2048,16]   f32
    float* hfin  = Ct + (size_t)MROWS * DSTATE;         // [4096,32,16] f32  8 MB
    float* dsums = hfin + (size_t)CH * NCHUNK * DSTATE; // [4096,32]   f32  0.5 MB
    unsigned short* xb   = (unsigned short*)(dsums + (size_t)CH * NCHUNK); // [2048,1024] bf16 4 MB
    unsigned short* wbuf = xb + (size_t)MROWS * DIM;        // up to 4M bf16   8 MB
    unsigned short* xcb  = wbuf + (size_t)4 * 1024 * 1024;  // [2048,2048] bf16 8 MB
    unsigned short* ygb  = xcb + (size_t)MROWS * DIN;       // [2048,2048] bf16 8 MB

    // region-reuse views (fp32) for split-K partials
    float* hfinF  = hfin;                                   // 8 MB: G2 P1 rows<1024; later G3 Q2
    float* ygbF   = (float*)ygb;                            // 8 MB: G2 P1 rows>=1024 (pre-offset)
    float* xcbF   = (float*)xcb;                            // 8 MB: G3 Q3
    const size_t SZ3 = (size_t)MROWS * DIM;                 // 2M floats = 8 MB

    // 1. xz = x @ W_in^T   [2048,4096], K=1024 -> 512 blocks (2/CU), plain
    f32_to_bf16<<<(MROWS * DIM) / 1024, 256, 0, stream>>>(x, xb, MROWS * DIM);
    f32_to_bf16<<<(2 * DIN * DIM) / 1024, 256, 0, stream>>>(W_in, wbuf, 2 * DIN * DIM);
    gemm_bf16<0><<<dim3((2 * DIN) / 128, MROWS / 128, 1), 256, 0, stream>>>(
        xb, wbuf, MROWS, 2 * DIN, DIM, DIM, xz, nullptr, nullptr, nullptr);

    // 2. causal conv + silu -> xcb (bf16)
    conv_silu<<<(MROWS * DIN) / 256, 256, 0, stream>>>(xz, W_conv, b_conv, xcb);

    // 3. delta partials: z=2 split (512 blocks, 2/CU), plain stores.
    //    P0 = delta region; P1 = hfin (rows<1024) / ygb-as-f32 (rows>=1024).
    f32_to_bf16<<<(DIN * DIN) / 1024, 256, 0, stream>>>(W_dt, wbuf, DIN * DIN);
    gemm_bf16<1><<<dim3(DIN / 128, MROWS / 128, 2), 256, 0, stream>>>(
        xcb, wbuf, MROWS, DIN, DIN, DIN / 2,
        delta, hfinF, ygbF - (size_t)1024 * DIN, nullptr);
    finalize_delta<<<(MROWS * DIN) / 1024, 256, 0, stream>>>(
        delta, hfinF, ygbF - (size_t)1024 * DIN, b_dt);

    // 4. B_t, C_t projections
    bc_proj<<<MROWS, 256, 0, stream>>>(xcb, W_B, W_C, Bt, Ct);

    // 5. chunked selective scan -> ygb (bf16; safe: finalize consumed P1hi)
    scan_pass1<<<dim3(CH / 256, NCHUNK), 256, 0, stream>>>(
        delta, xcb, Bt, A_log, hfin, dsums);
    scan_pass2<<<(CH * DSTATE) / 256, 256, 0, stream>>>(hfin, dsums, A_log);
    scan_pass3<<<dim3(CH / 256, NCHUNK), 256, 0, stream>>>(
        delta, xcb, Bt, Ct, xz, A_log, Dvec, hfin, ygb);

    // 6. out partials: z=4 split (512 blocks, 2/CU), plain stores into
    //    dead regions: Q0,Q1 = delta region; Q2 = hfin; Q3 = xcb region.
    f32_to_bf16<<<(DIM * DIN) / 1024, 256, 0, stream>>>(W_out, wbuf, DIM * DIN);
    gemm_bf16<2><<<dim3(DIM / 128, MROWS / 128, 4), 256, 0, stream>>>(
        ygb, wbuf, MROWS, DIM, DIN, DIN / 4,
        delta, delta + SZ3, hfinF, xcbF);
    out_combine<<<(MROWS * DIM) / 1024, 256, 0, stream>>>(
        x, delta, delta + SZ3, hfinF, xcbF, out);
}